// Round 8
// baseline (2317.906 us; speedup 1.0000x reference)
//
#include <hip/hip_runtime.h>
#include <hip/hip_bf16.h>

#define BATCH 4
#define TLEN 16384
#define CH 128
#define HC 64
#define TPRIME 10246
#define LDIFF 3069
#define NLAYERS 30
#define FC1C 2048
#define FC2C 256

typedef short bf16x8 __attribute__((ext_vector_type(8)));
typedef float f32x4 __attribute__((ext_vector_type(4)));
#define MFMA(a, b, c) __builtin_amdgcn_mfma_f32_16x16x32_bf16(a, b, c, 0, 0, 0)

static __device__ __forceinline__ short f2b(float f) {
    __hip_bfloat16 h = __float2bfloat16(f);
    return *reinterpret_cast<short*>(&h);
}
static __device__ __forceinline__ float b2f(short s) {
    __hip_bfloat16 h;
    *reinterpret_cast<short*>(&h) = s;
    return __bfloat162float(h);
}

// ---------------------------------------------------------------- MFMA weight packer (PROVEN r3-r6)
// out layout: [cob][tap][kc][kg(4)][co(128)][j(8)]  (bf16), ci = kc*32+kg*8+j
__global__ void k_prep_conv(const float* __restrict__ W, short* __restrict__ Wp,
                            int CIN, int KC, int total) {
    int o = blockIdx.x * 256 + threadIdx.x;
    if (o >= total) return;
    int j = o & 7;
    int co = (o >> 3) & 127;
    int kg = (o >> 10) & 3;
    int rest = o >> 12;       // = (cob*3+tap)*KC + kc
    int kc = rest % KC;
    int ct = rest / KC;
    int tap = ct % 3;
    int cob = ct / 3;
    int ci = kc * 32 + kg * 8 + j;
    int cog = cob * 128 + co;
    Wp[o] = f2b(W[((size_t)cog * CIN + ci) * 3 + tap]);
}

// skip/res 1x1 weights: out [layer][kg(8)][co(128)][j(8)], cz = kg*8+j (PROVEN r4-r6)
__global__ void k_prep_sr(const float* __restrict__ Ws, const float* __restrict__ Wr,
                          short* __restrict__ Wsp, short* __restrict__ Wrp) {
    int o = blockIdx.x * 256 + threadIdx.x;
    if (o >= NLAYERS * 8192) return;
    int j = o & 7;
    int co = (o >> 3) & 127;
    int kg = (o >> 10) & 7;
    int lay = o >> 13;
    size_t in = ((size_t)lay * 128 + co) * 64 + kg * 8 + j;
    Wsp[o] = f2b(Ws[in]);
    Wrp[o] = f2b(Wr[in]);
}

// ---------------------------------------------------------------- first conv -> h[b][t][c] bf16 (PROVEN r4)
__global__ __launch_bounds__(256) void k_first(const float* __restrict__ x,
                                               const float* __restrict__ Wf,
                                               short* __restrict__ h) {
    int gid = blockIdx.x * 256 + threadIdx.x;   // B*T*32 units of 4 co
    int co4 = (gid & 31) * 4;
    int t = (gid >> 5) & (TLEN - 1);
    int b = gid >> 19;
    const float* xb = x + (size_t)b * TLEN;
    float xm = t > 0 ? xb[t - 1] : 0.f;
    float x0 = xb[t];
    float xp = t < TLEN - 1 ? xb[t + 1] : 0.f;
    short4 o;
    float r[4];
#pragma unroll
    for (int i = 0; i < 4; ++i) {
        const float* wp = Wf + (co4 + i) * 3;
        r[i] = wp[0] * xm + wp[1] * x0 + wp[2] * xp;
    }
    o.x = f2b(r[0]); o.y = f2b(r[1]); o.z = f2b(r[2]); o.w = f2b(r[3]);
    *(short4*)(h + (size_t)b * TLEN * CH + (size_t)t * CH + co4) = o;
}

// ---------------------------------------------------------------- layer kernel v7 (unchanged from r7)
__global__ __launch_bounds__(256) void k_layer(
    const short* __restrict__ hin, short* __restrict__ hout,
    float* __restrict__ skips,              // [b][t'][c] fp32
    const short* __restrict__ Wp,           // [3][4][4][128][8] this layer
    const short* __restrict__ Wsp,          // [8][128][8] this layer
    const short* __restrict__ Wrp,
    int d) {
    __shared__ __align__(16) char smem[69632];   // region1 34816 + region2 34816
    int4*  R1  = (int4*)smem;                    // B stage [tt128][17 int4]
    short* R1s = (short*)smem;                   // same, [tt][136] shorts
    float* SK  = (float*)smem;                   // skips stage [64][132] fp32 (late)
    short* SZ  = (short*)(smem + 34816);         // z [kg8][tt128][j8] = 16 KB
    short* R2s = (short*)(smem + 34816);         // h_out stage [tt][136]
    int4*  R2  = (int4*)(smem + 34816);
    const int tid = threadIdx.x;
    const int l = tid & 63;
    const int w = tid >> 6;
    const int lm = l & 15;
    const int quad = l >> 4;
    const int b = blockIdx.y;
    const int t0 = blockIdx.x * 128;
    const int tq = w * 32;
    const short* hb = hin + (size_t)b * TLEN * CH;
    const bf16x8* Wg = (const bf16x8*)Wp;

    f32x4 acc[8][2] = {};
    const int taporder[3] = {0, 2, 1};           // tap=1 last -> R1 = h_in tile
#pragma unroll
    for (int ti = 0; ti < 3; ++ti) {
        const int tap = taporder[ti];
        const int toff = (tap - 1) * d;
        __syncthreads();
        for (int u = tid; u < 2048; u += 256) {  // coalesced: kg fastest
            int tt = u >> 4, kg = u & 15;
            int tg = t0 + tt + toff;
            int4 v = make_int4(0, 0, 0, 0);
            if ((unsigned)tg < TLEN)
                v = *(const int4*)(hb + (size_t)tg * CH + kg * 8);
            R1[tt * 17 + kg] = v;
        }
        __syncthreads();
#pragma unroll
        for (int kc = 0; kc < 4; ++kc) {
            bf16x8 af[8], bfr[2];
#pragma unroll
            for (int i = 0; i < 8; ++i)
                af[i] = Wg[(tap * 4 + kc) * 512 + quad * 128 + i * 16 + lm];
#pragma unroll
            for (int j = 0; j < 2; ++j)
                bfr[j] = *(const bf16x8*)(R1 + (tq + j * 16 + lm) * 17 + kc * 4 + quad);
#pragma unroll
            for (int i = 0; i < 8; ++i)
#pragma unroll
                for (int j = 0; j < 2; ++j)
                    acc[i][j] = MFMA(af[i], bfr[j], acc[i][j]);
        }
    }

    // ---- GLU in-register, z -> SZ in B-operand layout (PROVEN r4-r6)
#pragma unroll
    for (int i = 0; i < 4; ++i)
#pragma unroll
        for (int j = 0; j < 2; ++j) {
            short zo[4];
#pragma unroll
            for (int r = 0; r < 4; ++r) {
                float a = acc[i][j][r];
                float g = acc[i + 4][j][r];
                float th = tanhf(a);
                float sg = 1.f / (1.f + __expf(-g));
                zo[r] = f2b(th * sg);
            }
            int co = i * 16 + quad * 4;
            int kg = co >> 3;
            int jj0 = co & 7;
            short4 zv = {zo[0], zo[1], zo[2], zo[3]};
            *(short4*)(SZ + (kg * 128 + tq + j * 16 + lm) * 8 + jj0) = zv;
        }
    __syncthreads();

    // ---- skip/res GEMMs, K=64; weights direct from global (PROVEN r5/r6)
    const bf16x8* Wsg = (const bf16x8*)Wsp;
    const bf16x8* Wrg = (const bf16x8*)Wrp;
    f32x4 aS[8][2] = {}, aR[8][2] = {};
#pragma unroll
    for (int kk = 0; kk < 2; ++kk) {
        int kgg = kk * 4 + quad;
        bf16x8 zs[2], wsf[8], wrf[8];
#pragma unroll
        for (int j = 0; j < 2; ++j)
            zs[j] = *(const bf16x8*)(SZ + (kgg * 128 + tq + j * 16 + lm) * 8);
#pragma unroll
        for (int i = 0; i < 8; ++i) {
            wsf[i] = Wsg[kgg * 128 + i * 16 + lm];
            wrf[i] = Wrg[kgg * 128 + i * 16 + lm];
        }
#pragma unroll
        for (int i = 0; i < 8; ++i)
#pragma unroll
            for (int j = 0; j < 2; ++j) {
                aS[i][j] = MFMA(wsf[i], zs[j], aS[i][j]);
                aR[i][j] = MFMA(wrf[i], zs[j], aR[i][j]);
            }
    }
    __syncthreads();   // SZ reads done; region2 becomes h_out stage

    // ---- h_out: residual from R1 (h_in tile in LDS), stage to R2, coalesced copy
    const float scale = 0.70710678118654752f;
#pragma unroll
    for (int i = 0; i < 8; ++i)
#pragma unroll
        for (int j = 0; j < 2; ++j) {
            int tt = tq + j * 16 + lm;
            int co = i * 16 + quad * 4;
            short4 hv = *(const short4*)(R1s + tt * 136 + co);
            short4 ho;
            ho.x = f2b((b2f(hv.x) + aR[i][j][0]) * scale);
            ho.y = f2b((b2f(hv.y) + aR[i][j][1]) * scale);
            ho.z = f2b((b2f(hv.z) + aR[i][j][2]) * scale);
            ho.w = f2b((b2f(hv.w) + aR[i][j][3]) * scale);
            *(short4*)(R2s + tt * 136 + co) = ho;
        }
    __syncthreads();
    short* hob = hout + (size_t)b * TLEN * CH;
    for (int u = tid; u < 2048; u += 256) {
        int tt = u >> 4, kg = u & 15;
        *(int4*)(hob + (size_t)(t0 + tt) * CH + kg * 8) = R2[tt * 17 + kg];
    }

    // ---- skips: stage fp32 partials in R1 area, coalesced RMW; 2 half-tiles
    const bool anyskip = (t0 + 127 >= LDIFF) && (t0 < LDIFF + TPRIME);
    if (anyskip) {
        float* skb = skips + (size_t)b * TPRIME * CH;
#pragma unroll
        for (int p = 0; p < 2; ++p) {
            __syncthreads();
            if ((tq >> 6) == p) {
#pragma unroll
                for (int i = 0; i < 8; ++i)
#pragma unroll
                    for (int j = 0; j < 2; ++j) {
                        int tt = tq + j * 16 + lm - p * 64;
                        int co = i * 16 + quad * 4;
                        float4 v = make_float4(aS[i][j][0], aS[i][j][1],
                                               aS[i][j][2], aS[i][j][3]);
                        *(float4*)(SK + tt * 132 + co) = v;
                    }
            }
            __syncthreads();
            for (int u = tid; u < 2048; u += 256) {
                int tt = u >> 5, cg = u & 31;
                int ts = t0 + p * 64 + tt - LDIFF;
                if ((unsigned)ts < TPRIME) {
                    float4* sp = (float4*)(skb + (size_t)ts * CH + cg * 4);
                    float4 sv = *sp;
                    float4 av = *(const float4*)(SK + tt * 132 + cg * 4);
                    sv.x += av.x; sv.y += av.y; sv.z += av.z; sv.w += av.w;
                    *sp = sv;
                }
            }
        }
    }
}

// ---------------------------- skips fp32 [b][t'][c] -> relu -> bf16 (PROVEN r4)
__global__ __launch_bounds__(256) void k_skipcvt(const float* __restrict__ sk,
                                                 short* __restrict__ sbf) {
    int gid = blockIdx.x * 256 + threadIdx.x;
    size_t base = (size_t)gid * 4;
    float4 v = *(const float4*)(sk + base);
    short4 o;
    o.x = f2b(fmaxf(v.x, 0.f)); o.y = f2b(fmaxf(v.y, 0.f));
    o.z = f2b(fmaxf(v.z, 0.f)); o.w = f2b(fmaxf(v.w, 0.f));
    *(short4*)(sbf + base) = o;
}

// ---------------------------------------------------------------- fused head: fc1+fc2+1x1+bias
// FIX r8: Y rows whose t' = t0-1+row falls outside [0,TPRIME) are ZEROED
// (reference pads y1 with zeros for fc2's 'same' conv).
__global__ __launch_bounds__(256) void k_head(
    const short* __restrict__ sbf,
    const short* __restrict__ Wp1,   // [16][3][4][4][128][8]
    const short* __restrict__ Wp2,   // [2][3][64][4][128][8]
    const float* __restrict__ Wlast,
    const float* __restrict__ blast,
    float* __restrict__ out) {
    __shared__ __align__(16) char smem[36448];   // SB1 18496 + Y 17952
    int4*  SB1 = (int4*)smem;                    // [68 rows][17 int4]
    short* Y   = (short*)(smem + 18496);         // [66 rows][136 shorts]
    __shared__ float red[64];
    const int tid = threadIdx.x;
    const int l = tid & 63;
    const int w = tid >> 6;
    const int lm = l & 15;
    const int quad = l >> 4;
    const int b = blockIdx.y;
    const int t0 = blockIdx.x * 64;
    const short* sb = sbf + (size_t)b * TPRIME * CH;

    // stage sbf rows t0-2 .. t0+65 (coalesced)
    for (int u = tid; u < 1088; u += 256) {
        int tt = u >> 4, kg = u & 15;
        int tg = t0 - 2 + tt;
        int4 v = make_int4(0, 0, 0, 0);
        if ((unsigned)tg < TPRIME)
            v = *(const int4*)(sb + (size_t)tg * CH + kg * 8);
        SB1[tt * 17 + kg] = v;
    }
    if (tid < 64) red[tid] = 0.f;
    __syncthreads();

    const bf16x8* W1 = (const bf16x8*)Wp1;
    const bf16x8* W2 = (const bf16x8*)Wp2;
    const int cob2 = w >> 1;
    const int coq2 = (w & 1) * 64;
    f32x4 acc2[4][4] = {};

    for (int cic = 0; cic < 16; ++cic) {
        // ---- fc1 chunk: 128 co, out rows 0..65 (t = t0-1+row)
        f32x4 acc1[2][5] = {};
#pragma unroll
        for (int tap = 0; tap < 3; ++tap)
#pragma unroll
            for (int kc = 0; kc < 4; ++kc) {
                bf16x8 a1[2], b1[5];
#pragma unroll
                for (int i = 0; i < 2; ++i)
                    a1[i] = W1[((size_t)(cic * 3 + tap) * 4 + kc) * 512 +
                               quad * 128 + 32 * w + i * 16 + lm];
#pragma unroll
                for (int j = 0; j < 5; ++j) {
                    int r = j * 16 + lm + tap;   // input row (guarded at write)
                    b1[j] = *(const bf16x8*)(SB1 + r * 17 + kc * 4 + quad);
                }
#pragma unroll
                for (int i = 0; i < 2; ++i)
#pragma unroll
                    for (int j = 0; j < 5; ++j)
                        acc1[i][j] = MFMA(a1[i], b1[j], acc1[i][j]);
            }
        __syncthreads();              // previous chunk's Y reads done
#pragma unroll
        for (int i = 0; i < 2; ++i)
#pragma unroll
            for (int j = 0; j < 5; ++j) {
                int row = j * 16 + lm;
                if (row < 66) {
                    int co = 32 * w + i * 16 + quad * 4;
                    const bool valid = (unsigned)(t0 - 1 + row) < TPRIME;  // FIX r8
                    short4 v;
                    v.x = valid ? f2b(fmaxf(acc1[i][j][0], 0.f)) : (short)0;
                    v.y = valid ? f2b(fmaxf(acc1[i][j][1], 0.f)) : (short)0;
                    v.z = valid ? f2b(fmaxf(acc1[i][j][2], 0.f)) : (short)0;
                    v.w = valid ? f2b(fmaxf(acc1[i][j][3], 0.f)) : (short)0;
                    *(short4*)(Y + row * 136 + co) = v;
                }
            }
        __syncthreads();
        // ---- fc2 partial over this chunk's 128 ci x 3 taps
#pragma unroll
        for (int tap = 0; tap < 3; ++tap)
#pragma unroll
            for (int kc = 0; kc < 4; ++kc) {
                bf16x8 a2[4], b2[4];
#pragma unroll
                for (int i = 0; i < 4; ++i)
                    a2[i] = W2[((size_t)(cob2 * 3 + tap) * 64 + cic * 4 + kc) * 512 +
                               quad * 128 + coq2 + i * 16 + lm];
#pragma unroll
                for (int j = 0; j < 4; ++j) {
                    int row = j * 16 + lm + tap;   // out t = t0 + j*16+lm; y row = t+toff-(t0-1)
                    b2[j] = *(const bf16x8*)(Y + row * 136 + kc * 32 + quad * 8);
                }
#pragma unroll
                for (int i = 0; i < 4; ++i)
#pragma unroll
                    for (int j = 0; j < 4; ++j)
                        acc2[i][j] = MFMA(a2[i], b2[j], acc2[i][j]);
            }
    }

    // ---- fused 1x1 head + bias (out written exactly once)
    float4 wv[4];
#pragma unroll
    for (int i = 0; i < 4; ++i)
        wv[i] = *(const float4*)(Wlast + cob2 * 128 + coq2 + i * 16 + quad * 4);
#pragma unroll
    for (int j = 0; j < 4; ++j) {
        float s = 0.f;
#pragma unroll
        for (int i = 0; i < 4; ++i)
            s += wv[i].x * acc2[i][j][0] + wv[i].y * acc2[i][j][1] +
                 wv[i].z * acc2[i][j][2] + wv[i].w * acc2[i][j][3];
        atomicAdd(&red[j * 16 + lm], s);
    }
    __syncthreads();
    if (tid < 64) {
        int tg = t0 + tid;
        if (tg < TPRIME) out[(size_t)b * TPRIME + tg] = red[tid] + blast[0];
    }
}

extern "C" void kernel_launch(void* const* d_in, const int* in_sizes, int n_in,
                              void* d_out, int out_size, void* d_ws, size_t ws_size,
                              hipStream_t stream) {
    const float* x = (const float*)d_in[0];
    const float* Wf = (const float*)d_in[1];
    const float* Wdil = (const float*)d_in[2];
    const float* Wskip = (const float*)d_in[3];
    const float* Wres = (const float*)d_in[4];
    const float* Wfc1 = (const float*)d_in[5];
    const float* Wfc2 = (const float*)d_in[6];
    const float* Wlast = (const float*)d_in[7];
    const float* blast = (const float*)d_in[8];
    float* out = (float*)d_out;

    char* p = (char*)d_ws;
    auto alloc = [&](size_t bytes) { char* r = p; p += (bytes + 255) & ~(size_t)255; return r; };
    float* skips = (float*)alloc((size_t)BATCH * TPRIME * CH * 4);   // 21.0 MB [b][t'][c]
    short* WpD   = (short*)alloc((size_t)NLAYERS * 49152 * 2);       // 2.95 MB
    short* Wsp   = (short*)alloc((size_t)NLAYERS * 8192 * 2);
    short* Wrp   = (short*)alloc((size_t)NLAYERS * 8192 * 2);
    short* Wp1   = (short*)alloc((size_t)786432 * 2);                // 1.5 MB
    short* Wp2   = (short*)alloc((size_t)1572864 * 2);               // 3.0 MB
    short* hA    = (short*)alloc((size_t)BATCH * TLEN * CH * 2);     // 16.78 MB
    short* hB    = (short*)alloc((size_t)BATCH * TLEN * CH * 2);     // 16.78 MB
    short* sbf   = (short*)alloc((size_t)BATCH * TPRIME * CH * 2);   // 10.49 MB
    // total ~73 MB

    k_prep_conv<<<5760, 256, 0, stream>>>(Wdil, WpD, 128, 4, 1474560);
    k_prep_conv<<<3072, 256, 0, stream>>>(Wfc1, Wp1, 128, 4, 786432);
    k_prep_conv<<<6144, 256, 0, stream>>>(Wfc2, Wp2, 2048, 64, 1572864);
    k_prep_sr<<<960, 256, 0, stream>>>(Wskip, Wres, Wsp, Wrp);
    hipMemsetAsync(skips, 0, (size_t)BATCH * TPRIME * CH * 4, stream);
    k_first<<<8192, 256, 0, stream>>>(x, Wf, hA);

    short* hin = hA;
    short* hout = hB;
    for (int lyr = 0; lyr < NLAYERS; ++lyr) {
        int d = 1 << (lyr % 10);
        k_layer<<<dim3(TLEN / 128, BATCH), 256, 0, stream>>>(
            hin, hout, skips, WpD + (size_t)lyr * 49152,
            Wsp + (size_t)lyr * 8192, Wrp + (size_t)lyr * 8192, d);
        short* tmp = hin; hin = hout; hout = tmp;
    }

    k_skipcvt<<<5123, 256, 0, stream>>>(skips, sbf);
    k_head<<<dim3(161, BATCH), 256, 0, stream>>>(sbf, Wp1, Wp2, Wlast, blast, out);
}

// Round 9
// 1301.621 us; speedup vs baseline: 1.7808x; 1.7808x over previous
//
#include <hip/hip_runtime.h>
#include <hip/hip_bf16.h>

#define BATCH 4
#define TLEN 16384
#define CH 128
#define HC 64
#define TPRIME 10246
#define LDIFF 3069
#define NLAYERS 30
#define FC1C 2048
#define FC2C 256
#define ZK 1920              // 30 layers * 64 z-channels

typedef short bf16x8 __attribute__((ext_vector_type(8)));
typedef float f32x4 __attribute__((ext_vector_type(4)));
#define MFMA(a, b, c) __builtin_amdgcn_mfma_f32_16x16x32_bf16(a, b, c, 0, 0, 0)

static __device__ __forceinline__ short f2b(float f) {
    __hip_bfloat16 h = __float2bfloat16(f);
    return *reinterpret_cast<short*>(&h);
}
static __device__ __forceinline__ float b2f(short s) {
    __hip_bfloat16 h;
    *reinterpret_cast<short*>(&h) = s;
    return __bfloat162float(h);
}

// ---------------------------------------------------------------- MFMA weight packer (PROVEN r3-r8)
// out layout: [cob][tap][kc][kg(4)][co(128)][j(8)]  (bf16), ci = kc*32+kg*8+j
__global__ void k_prep_conv(const float* __restrict__ W, short* __restrict__ Wp,
                            int CIN, int KC, int total) {
    int o = blockIdx.x * 256 + threadIdx.x;
    if (o >= total) return;
    int j = o & 7;
    int co = (o >> 3) & 127;
    int kg = (o >> 10) & 3;
    int rest = o >> 12;       // = (cob*3+tap)*KC + kc
    int kc = rest % KC;
    int ct = rest / KC;
    int tap = ct % 3;
    int cob = ct / 3;
    int ci = kc * 32 + kg * 8 + j;
    int cog = cob * 128 + co;
    Wp[o] = f2b(W[((size_t)cog * CIN + ci) * 3 + tap]);
}

// skip/res 1x1 weights: out [layer][kg(8)][co(128)][j(8)], cz = kg*8+j (PROVEN r4-r8)
// NOTE: concatenated over layers this IS the K-major [kg240][co][j8] image for
// the fused skip GEMM (k = layer*64 + cz).
__global__ void k_prep_sr(const float* __restrict__ Ws, const float* __restrict__ Wr,
                          short* __restrict__ Wsp, short* __restrict__ Wrp) {
    int o = blockIdx.x * 256 + threadIdx.x;
    if (o >= NLAYERS * 8192) return;
    int j = o & 7;
    int co = (o >> 3) & 127;
    int kg = (o >> 10) & 7;
    int lay = o >> 13;
    size_t in = ((size_t)lay * 128 + co) * 64 + kg * 8 + j;
    Wsp[o] = f2b(Ws[in]);
    Wrp[o] = f2b(Wr[in]);
}

// ---------------------------------------------------------------- first conv -> h[b][t][c] bf16 (PROVEN r4)
__global__ __launch_bounds__(256) void k_first(const float* __restrict__ x,
                                               const float* __restrict__ Wf,
                                               short* __restrict__ h) {
    int gid = blockIdx.x * 256 + threadIdx.x;   // B*T*32 units of 4 co
    int co4 = (gid & 31) * 4;
    int t = (gid >> 5) & (TLEN - 1);
    int b = gid >> 19;
    const float* xb = x + (size_t)b * TLEN;
    float xm = t > 0 ? xb[t - 1] : 0.f;
    float x0 = xb[t];
    float xp = t < TLEN - 1 ? xb[t + 1] : 0.f;
    short4 o;
    float r[4];
#pragma unroll
    for (int i = 0; i < 4; ++i) {
        const float* wp = Wf + (co4 + i) * 3;
        r[i] = wp[0] * xm + wp[1] * x0 + wp[2] * xp;
    }
    o.x = f2b(r[0]); o.y = f2b(r[1]); o.z = f2b(r[2]); o.w = f2b(r[3]);
    *(short4*)(h + (size_t)b * TLEN * CH + (size_t)t * CH + co4) = o;
}

// ---------------------------------------------------------------- layer kernel v9
// r6 structure (direct-global fragments, zero conv barriers, small LDS) with the
// skip path removed: z (bf16) written to zbuf[b][t'][lyr*64+cz] instead of a
// 42MB/layer fp32 skips RMW. 64-t tiles -> 1024 blocks.
__global__ __launch_bounds__(256) void k_layer(
    const short* __restrict__ hin, short* __restrict__ hout,
    short* __restrict__ zlay,               // zbuf + lyr*64
    const short* __restrict__ Wp,           // [3][4][4][128][8] this layer
    const short* __restrict__ Wrp,          // [8][128][8] this layer
    int d) {
    __shared__ __align__(16) short SZ[4096];  // z: [kg8][tt64][j8] = 8 KB
    const int tid = threadIdx.x;
    const int l = tid & 63;
    const int w = tid >> 6;
    const int lm = l & 15;
    const int quad = l >> 4;
    const int b = blockIdx.y;
    const int t0 = blockIdx.x * 64;
    const int tq = w * 16;
    const short* hb = hin + (size_t)b * TLEN * CH;
    const bf16x8* Wg = (const bf16x8*)Wp;

    f32x4 acc[8] = {};
    for (int tap = 0; tap < 3; ++tap) {
        const int toff = (tap - 1) * d;
#pragma unroll
        for (int kc = 0; kc < 4; ++kc) {
            bf16x8 af[8], bfr;
#pragma unroll
            for (int i = 0; i < 8; ++i)
                af[i] = Wg[(tap * 4 + kc) * 512 + quad * 128 + i * 16 + lm];
            {
                int tg = t0 + tq + lm + toff;
                bf16x8 v = {};
                if ((unsigned)tg < TLEN)
                    v = *(const bf16x8*)(hb + (size_t)tg * CH + kc * 32 + quad * 8);
                bfr = v;
            }
#pragma unroll
            for (int i = 0; i < 8; ++i)
                acc[i] = MFMA(af[i], bfr, acc[i]);
        }
    }

    // ---- GLU in-register, z -> SZ in B-operand layout (PROVEN r4-r8)
#pragma unroll
    for (int i = 0; i < 4; ++i) {
        short zo[4];
#pragma unroll
        for (int r = 0; r < 4; ++r) {
            float a = acc[i][r];          // co = i*16+quad*4+r  (filter)
            float g = acc[i + 4][r];      // co + 64             (gate)
            float th = tanhf(a);
            float sg = 1.f / (1.f + __expf(-g));
            zo[r] = f2b(th * sg);
        }
        int co = i * 16 + quad * 4;       // cz in [0,64)
        int kg = co >> 3;
        int jj0 = co & 7;                 // 0 or 4
        short4 zv = {zo[0], zo[1], zo[2], zo[3]};
        *(short4*)(SZ + (kg * 64 + tq + lm) * 8 + jj0) = zv;
    }
    __syncthreads();

    // ---- res GEMM only, K=64; weights direct from global (PROVEN r5/r6)
    const bf16x8* Wrg = (const bf16x8*)Wrp;
    f32x4 aR[8] = {};
#pragma unroll
    for (int kk = 0; kk < 2; ++kk) {
        int kgg = kk * 4 + quad;
        bf16x8 zs, wrf[8];
        zs = *(const bf16x8*)(SZ + (kgg * 64 + tq + lm) * 8);
#pragma unroll
        for (int i = 0; i < 8; ++i)
            wrf[i] = Wrg[kgg * 128 + i * 16 + lm];
#pragma unroll
        for (int i = 0; i < 8; ++i)
            aR[i] = MFMA(wrf[i], zs, aR[i]);
    }

    // ---- h_out epilogue (r6-style)
    const float scale = 0.70710678118654752f;
    short* hob = hout + (size_t)b * TLEN * CH;
    {
        int tg = t0 + tq + lm;
#pragma unroll
        for (int i = 0; i < 8; ++i) {
            int co = i * 16 + quad * 4;
            short4 hv = *(const short4*)(hb + (size_t)tg * CH + co);
            short4 ho;
            ho.x = f2b((b2f(hv.x) + aR[i][0]) * scale);
            ho.y = f2b((b2f(hv.y) + aR[i][1]) * scale);
            ho.z = f2b((b2f(hv.z) + aR[i][2]) * scale);
            ho.w = f2b((b2f(hv.w) + aR[i][3]) * scale);
            *(short4*)(hob + (size_t)tg * CH + co) = ho;
        }
    }

    // ---- z -> global (only t' in range), 128B segments per tt
    short* zb = zlay + (size_t)b * TPRIME * ZK;
    for (int u = tid; u < 512; u += 256) {
        int tt = u >> 3, kg = u & 7;
        int ts = t0 + tt - LDIFF;
        if ((unsigned)ts < TPRIME)
            *(int4*)(zb + (size_t)ts * ZK + kg * 8) = *(const int4*)(SZ + (kg * 64 + tt) * 8);
    }
}

// ---------------------------------------------------------------- fused skip GEMM + relu -> sbf
// skips[t',c] = sum over k=layer*64+cz of Wsp[k][c] * z[t'][k]; K=1920.
// No LDS, no barriers: A (0.5MB, L2-resident) and B (streamed) direct from global.
__global__ __launch_bounds__(256) void k_skipgemm(
    const short* __restrict__ zbuf,   // [b][t'][1920]
    const short* __restrict__ Wsp,    // [kg240][co128][j8]
    short* __restrict__ sbf) {        // [b][t'][128]
    const int tid = threadIdx.x;
    const int l = tid & 63;
    const int w = tid >> 6;
    const int lm = l & 15;
    const int quad = l >> 4;
    const int b = blockIdx.y;
    const int t0 = blockIdx.x * 64;
    const int coq = (w & 1) * 64;
    const int tq = (w >> 1) * 32;
    const short* zb = zbuf + (size_t)b * TPRIME * ZK;
    const bf16x8* Wsg = (const bf16x8*)Wsp;

    f32x4 acc[4][2] = {};
    for (int kc = 0; kc < 60; ++kc) {
        bf16x8 af[4], bfr[2];
#pragma unroll
        for (int i = 0; i < 4; ++i)
            af[i] = Wsg[(kc * 4 + quad) * 128 + coq + i * 16 + lm];
#pragma unroll
        for (int j = 0; j < 2; ++j) {
            int tg = t0 + tq + j * 16 + lm;
            bf16x8 v = {};
            if (tg < TPRIME)
                v = *(const bf16x8*)(zb + (size_t)tg * ZK + kc * 32 + quad * 8);
            bfr[j] = v;
        }
#pragma unroll
        for (int i = 0; i < 4; ++i)
#pragma unroll
            for (int j = 0; j < 2; ++j)
                acc[i][j] = MFMA(af[i], bfr[j], acc[i][j]);
    }
    short* sb = sbf + (size_t)b * TPRIME * CH;
#pragma unroll
    for (int i = 0; i < 4; ++i)
#pragma unroll
        for (int j = 0; j < 2; ++j) {
            int tg = t0 + tq + j * 16 + lm;
            int co = coq + i * 16 + quad * 4;
            if (tg < TPRIME) {
                short4 v;
                v.x = f2b(fmaxf(acc[i][j][0], 0.f));
                v.y = f2b(fmaxf(acc[i][j][1], 0.f));
                v.z = f2b(fmaxf(acc[i][j][2], 0.f));
                v.w = f2b(fmaxf(acc[i][j][3], 0.f));
                *(short4*)(sb + (size_t)tg * CH + co) = v;
            }
        }
}

// ---------------------------------------------------------------- fused head (r8 + K-split x4)
// blockIdx.y = ks selects 4 of 16 fc1-output chunks; partials atomicAdd'ed into
// out (pre-initialized with bias by k_bias). Y edge rows zeroed (FIX r8, kept).
__global__ __launch_bounds__(256) void k_head(
    const short* __restrict__ sbf,
    const short* __restrict__ Wp1,   // [16][3][4][4][128][8]
    const short* __restrict__ Wp2,   // [2][3][64][4][128][8]
    const float* __restrict__ Wlast,
    float* __restrict__ out) {
    __shared__ __align__(16) char smem[36448];   // SB1 18496 + Y 17952
    int4*  SB1 = (int4*)smem;                    // [68 rows][17 int4]
    short* Y   = (short*)(smem + 18496);         // [66 rows][136 shorts]
    __shared__ float red[64];
    const int tid = threadIdx.x;
    const int l = tid & 63;
    const int w = tid >> 6;
    const int lm = l & 15;
    const int quad = l >> 4;
    const int ks = blockIdx.y;
    const int b = blockIdx.z;
    const int t0 = blockIdx.x * 64;
    const short* sb = sbf + (size_t)b * TPRIME * CH;

    for (int u = tid; u < 1088; u += 256) {
        int tt = u >> 4, kg = u & 15;
        int tg = t0 - 2 + tt;
        int4 v = make_int4(0, 0, 0, 0);
        if ((unsigned)tg < TPRIME)
            v = *(const int4*)(sb + (size_t)tg * CH + kg * 8);
        SB1[tt * 17 + kg] = v;
    }
    if (tid < 64) red[tid] = 0.f;
    __syncthreads();

    const bf16x8* W1 = (const bf16x8*)Wp1;
    const bf16x8* W2 = (const bf16x8*)Wp2;
    const int cob2 = w >> 1;
    const int coq2 = (w & 1) * 64;
    f32x4 acc2[4][4] = {};

    for (int cic = ks * 4; cic < ks * 4 + 4; ++cic) {
        f32x4 acc1[2][5] = {};
#pragma unroll
        for (int tap = 0; tap < 3; ++tap)
#pragma unroll
            for (int kc = 0; kc < 4; ++kc) {
                bf16x8 a1[2], b1[5];
#pragma unroll
                for (int i = 0; i < 2; ++i)
                    a1[i] = W1[((size_t)(cic * 3 + tap) * 4 + kc) * 512 +
                               quad * 128 + 32 * w + i * 16 + lm];
#pragma unroll
                for (int j = 0; j < 5; ++j) {
                    int r = j * 16 + lm + tap;
                    b1[j] = *(const bf16x8*)(SB1 + r * 17 + kc * 4 + quad);
                }
#pragma unroll
                for (int i = 0; i < 2; ++i)
#pragma unroll
                    for (int j = 0; j < 5; ++j)
                        acc1[i][j] = MFMA(a1[i], b1[j], acc1[i][j]);
            }
        __syncthreads();
#pragma unroll
        for (int i = 0; i < 2; ++i)
#pragma unroll
            for (int j = 0; j < 5; ++j) {
                int row = j * 16 + lm;
                if (row < 66) {
                    int co = 32 * w + i * 16 + quad * 4;
                    const bool valid = (unsigned)(t0 - 1 + row) < TPRIME;
                    short4 v;
                    v.x = valid ? f2b(fmaxf(acc1[i][j][0], 0.f)) : (short)0;
                    v.y = valid ? f2b(fmaxf(acc1[i][j][1], 0.f)) : (short)0;
                    v.z = valid ? f2b(fmaxf(acc1[i][j][2], 0.f)) : (short)0;
                    v.w = valid ? f2b(fmaxf(acc1[i][j][3], 0.f)) : (short)0;
                    *(short4*)(Y + row * 136 + co) = v;
                }
            }
        __syncthreads();
#pragma unroll
        for (int tap = 0; tap < 3; ++tap)
#pragma unroll
            for (int kc = 0; kc < 4; ++kc) {
                bf16x8 a2[4], b2[4];
#pragma unroll
                for (int i = 0; i < 4; ++i)
                    a2[i] = W2[((size_t)(cob2 * 3 + tap) * 64 + cic * 4 + kc) * 512 +
                               quad * 128 + coq2 + i * 16 + lm];
#pragma unroll
                for (int j = 0; j < 4; ++j) {
                    int row = j * 16 + lm + tap;
                    b2[j] = *(const bf16x8*)(Y + row * 136 + kc * 32 + quad * 8);
                }
#pragma unroll
                for (int i = 0; i < 4; ++i)
#pragma unroll
                    for (int j = 0; j < 4; ++j)
                        acc2[i][j] = MFMA(a2[i], b2[j], acc2[i][j]);
            }
    }

    float4 wv[4];
#pragma unroll
    for (int i = 0; i < 4; ++i)
        wv[i] = *(const float4*)(Wlast + cob2 * 128 + coq2 + i * 16 + quad * 4);
#pragma unroll
    for (int j = 0; j < 4; ++j) {
        float s = 0.f;
#pragma unroll
        for (int i = 0; i < 4; ++i)
            s += wv[i].x * acc2[i][j][0] + wv[i].y * acc2[i][j][1] +
                 wv[i].z * acc2[i][j][2] + wv[i].w * acc2[i][j][3];
        atomicAdd(&red[j * 16 + lm], s);
    }
    __syncthreads();
    if (tid < 64) {
        int tg = t0 + tid;
        if (tg < TPRIME) atomicAdd(&out[(size_t)b * TPRIME + tg], red[tid]);
    }
}

// ---------------------------------------------------------------- bias init (PROVEN r4)
__global__ void k_bias(float* __restrict__ out, const float* __restrict__ bl) {
    int i = blockIdx.x * 256 + threadIdx.x;
    if (i < BATCH * TPRIME) out[i] = bl[0];
}

extern "C" void kernel_launch(void* const* d_in, const int* in_sizes, int n_in,
                              void* d_out, int out_size, void* d_ws, size_t ws_size,
                              hipStream_t stream) {
    const float* x = (const float*)d_in[0];
    const float* Wf = (const float*)d_in[1];
    const float* Wdil = (const float*)d_in[2];
    const float* Wskip = (const float*)d_in[3];
    const float* Wres = (const float*)d_in[4];
    const float* Wfc1 = (const float*)d_in[5];
    const float* Wfc2 = (const float*)d_in[6];
    const float* Wlast = (const float*)d_in[7];
    const float* blast = (const float*)d_in[8];
    float* out = (float*)d_out;

    char* p = (char*)d_ws;
    auto alloc = [&](size_t bytes) { char* r = p; p += (bytes + 255) & ~(size_t)255; return r; };
    short* zbuf  = (short*)alloc((size_t)BATCH * TPRIME * ZK * 2);   // 157.4 MB
    short* WpD   = (short*)alloc((size_t)NLAYERS * 49152 * 2);       // 2.95 MB
    short* Wsp   = (short*)alloc((size_t)NLAYERS * 8192 * 2);        // 0.49 MB (K-major image)
    short* Wrp   = (short*)alloc((size_t)NLAYERS * 8192 * 2);        // 0.49 MB
    short* Wp1   = (short*)alloc((size_t)786432 * 2);                // 1.5 MB
    short* Wp2   = (short*)alloc((size_t)1572864 * 2);               // 3.0 MB
    short* hA    = (short*)alloc((size_t)BATCH * TLEN * CH * 2);     // 16.78 MB
    short* hB    = (short*)alloc((size_t)BATCH * TLEN * CH * 2);     // 16.78 MB
    short* sbf   = (short*)alloc((size_t)BATCH * TPRIME * CH * 2);   // 10.49 MB
    // total ~210 MB (<= 256 MiB ws, 208 MB proven r5)

    k_prep_conv<<<5760, 256, 0, stream>>>(Wdil, WpD, 128, 4, 1474560);
    k_prep_conv<<<3072, 256, 0, stream>>>(Wfc1, Wp1, 128, 4, 786432);
    k_prep_conv<<<6144, 256, 0, stream>>>(Wfc2, Wp2, 2048, 64, 1572864);
    k_prep_sr<<<960, 256, 0, stream>>>(Wskip, Wres, Wsp, Wrp);
    k_first<<<8192, 256, 0, stream>>>(x, Wf, hA);

    short* hin = hA;
    short* hout = hB;
    for (int lyr = 0; lyr < NLAYERS; ++lyr) {
        int d = 1 << (lyr % 10);
        k_layer<<<dim3(TLEN / 64, BATCH), 256, 0, stream>>>(
            hin, hout, zbuf + (size_t)lyr * 64,
            WpD + (size_t)lyr * 49152, Wrp + (size_t)lyr * 8192, d);
        short* tmp = hin; hin = hout; hout = tmp;
    }

    k_skipgemm<<<dim3(161, BATCH), 256, 0, stream>>>(zbuf, Wsp, sbf);
    k_bias<<<161, 256, 0, stream>>>(out, blast);
    k_head<<<dim3(161, 4, BATCH), 256, 0, stream>>>(sbf, Wp1, Wp2, Wlast, out);
}

// Round 10
// 1175.841 us; speedup vs baseline: 1.9713x; 1.1070x over previous
//
#include <hip/hip_runtime.h>
#include <hip/hip_bf16.h>

#define BATCH 4
#define TLEN 16384
#define CH 128
#define HC 64
#define TPRIME 10246
#define LDIFF 3069
#define NLAYERS 30
#define FC1C 2048
#define FC2C 256
#define ZK 1920              // 30 layers * 64 z-channels

typedef short bf16x8 __attribute__((ext_vector_type(8)));
typedef float f32x4 __attribute__((ext_vector_type(4)));
#define MFMA(a, b, c) __builtin_amdgcn_mfma_f32_16x16x32_bf16(a, b, c, 0, 0, 0)

static __device__ __forceinline__ short f2b(float f) {
    __hip_bfloat16 h = __float2bfloat16(f);
    return *reinterpret_cast<short*>(&h);
}
static __device__ __forceinline__ float b2f(short s) {
    __hip_bfloat16 h;
    *reinterpret_cast<short*>(&h) = s;
    return __bfloat162float(h);
}

// ---------------------------------------------------------------- MFMA weight packer (PROVEN r3-r9)
// out layout: [cob][tap][kc][kg(4)][co(128)][j(8)]  (bf16), ci = kc*32+kg*8+j
__global__ void k_prep_conv(const float* __restrict__ W, short* __restrict__ Wp,
                            int CIN, int KC, int total) {
    int o = blockIdx.x * 256 + threadIdx.x;
    if (o >= total) return;
    int j = o & 7;
    int co = (o >> 3) & 127;
    int kg = (o >> 10) & 3;
    int rest = o >> 12;       // = (cob*3+tap)*KC + kc
    int kc = rest % KC;
    int ct = rest / KC;
    int tap = ct % 3;
    int cob = ct / 3;
    int ci = kc * 32 + kg * 8 + j;
    int cog = cob * 128 + co;
    Wp[o] = f2b(W[((size_t)cog * CIN + ci) * 3 + tap]);
}

// skip/res 1x1 weights: out [layer][kg(8)][co(128)][j(8)], cz = kg*8+j (PROVEN r4-r9)
// Concatenated over layers = K-major [kg240][co][j8] image for the skip GEMM.
__global__ void k_prep_sr(const float* __restrict__ Ws, const float* __restrict__ Wr,
                          short* __restrict__ Wsp, short* __restrict__ Wrp) {
    int o = blockIdx.x * 256 + threadIdx.x;
    if (o >= NLAYERS * 8192) return;
    int j = o & 7;
    int co = (o >> 3) & 127;
    int kg = (o >> 10) & 7;
    int lay = o >> 13;
    size_t in = ((size_t)lay * 128 + co) * 64 + kg * 8 + j;
    Wsp[o] = f2b(Ws[in]);
    Wrp[o] = f2b(Wr[in]);
}

// ---------------------------------------------------------------- first conv -> h[b][t][c] bf16 (PROVEN r4)
__global__ __launch_bounds__(256) void k_first(const float* __restrict__ x,
                                               const float* __restrict__ Wf,
                                               short* __restrict__ h) {
    int gid = blockIdx.x * 256 + threadIdx.x;   // B*T*32 units of 4 co
    int co4 = (gid & 31) * 4;
    int t = (gid >> 5) & (TLEN - 1);
    int b = gid >> 19;
    const float* xb = x + (size_t)b * TLEN;
    float xm = t > 0 ? xb[t - 1] : 0.f;
    float x0 = xb[t];
    float xp = t < TLEN - 1 ? xb[t + 1] : 0.f;
    short4 o;
    float r[4];
#pragma unroll
    for (int i = 0; i < 4; ++i) {
        const float* wp = Wf + (co4 + i) * 3;
        r[i] = wp[0] * xm + wp[1] * x0 + wp[2] * xp;
    }
    o.x = f2b(r[0]); o.y = f2b(r[1]); o.z = f2b(r[2]); o.w = f2b(r[3]);
    *(short4*)(h + (size_t)b * TLEN * CH + (size_t)t * CH + co4) = o;
}

// ---------------------------------------------------------------- layer kernel v10
// r9 conv (direct-global fragments, zero conv barriers) + LDS-staged epilogue:
// h tile staged coalesced into HT, residual RMW in-place in LDS (race-free:
// each lane owns its address), coalesced copy-out. 2 barriers, 26 KB LDS.
__global__ __launch_bounds__(256) void k_layer(
    const short* __restrict__ hin, short* __restrict__ hout,
    short* __restrict__ zlay,               // zbuf + lyr*64
    const short* __restrict__ Wp,           // [3][4][4][128][8] this layer
    const short* __restrict__ Wrp,          // [8][128][8] this layer
    int d) {
    __shared__ __align__(16) short SZ[4096];      // z: [kg8][tt64][j8] = 8 KB
    __shared__ __align__(16) short HT[8704];      // h tile [tt64][136] = 17 KB
    const int tid = threadIdx.x;
    const int l = tid & 63;
    const int w = tid >> 6;
    const int lm = l & 15;
    const int quad = l >> 4;
    const int b = blockIdx.y;
    const int t0 = blockIdx.x * 64;
    const int tq = w * 16;
    const short* hb = hin + (size_t)b * TLEN * CH;
    const bf16x8* Wg = (const bf16x8*)Wp;

    f32x4 acc[8] = {};
    for (int tap = 0; tap < 3; ++tap) {
        const int toff = (tap - 1) * d;
#pragma unroll
        for (int kc = 0; kc < 4; ++kc) {
            bf16x8 af[8], bfr;
#pragma unroll
            for (int i = 0; i < 8; ++i)
                af[i] = Wg[(tap * 4 + kc) * 512 + quad * 128 + i * 16 + lm];
            {
                int tg = t0 + tq + lm + toff;
                bf16x8 v = {};
                if ((unsigned)tg < TLEN)
                    v = *(const bf16x8*)(hb + (size_t)tg * CH + kc * 32 + quad * 8);
                bfr = v;
            }
#pragma unroll
            for (int i = 0; i < 8; ++i)
                acc[i] = MFMA(af[i], bfr, acc[i]);
        }
    }

    // ---- stage h_in tile coalesced (no barrier needed; HT disjoint from SZ)
    int4* HT4 = (int4*)HT;
    for (int u = tid; u < 1024; u += 256) {
        int tt = u >> 4, kg = u & 15;
        HT4[tt * 17 + kg] = *(const int4*)(hb + (size_t)(t0 + tt) * CH + kg * 8);
    }

    // ---- GLU in-register, z -> SZ in B-operand layout (PROVEN r4-r9)
#pragma unroll
    for (int i = 0; i < 4; ++i) {
        short zo[4];
#pragma unroll
        for (int r = 0; r < 4; ++r) {
            float a = acc[i][r];          // co = i*16+quad*4+r  (filter)
            float g = acc[i + 4][r];      // co + 64             (gate)
            float th = tanhf(a);
            float sg = 1.f / (1.f + __expf(-g));
            zo[r] = f2b(th * sg);
        }
        int co = i * 16 + quad * 4;       // cz in [0,64)
        int kg = co >> 3;
        int jj0 = co & 7;                 // 0 or 4
        short4 zv = {zo[0], zo[1], zo[2], zo[3]};
        *(short4*)(SZ + (kg * 64 + tq + lm) * 8 + jj0) = zv;
    }
    __syncthreads();                       // covers SZ writes AND HT staging

    // ---- res GEMM, K=64; weights direct from global (PROVEN r5-r9)
    const bf16x8* Wrg = (const bf16x8*)Wrp;
    f32x4 aR[8] = {};
#pragma unroll
    for (int kk = 0; kk < 2; ++kk) {
        int kgg = kk * 4 + quad;
        bf16x8 zs, wrf[8];
        zs = *(const bf16x8*)(SZ + (kgg * 64 + tq + lm) * 8);
#pragma unroll
        for (int i = 0; i < 8; ++i)
            wrf[i] = Wrg[kgg * 128 + i * 16 + lm];
#pragma unroll
        for (int i = 0; i < 8; ++i)
            aR[i] = MFMA(wrf[i], zs, aR[i]);
    }

    // ---- residual RMW in LDS (each lane owns its address -> race-free)
    const float scale = 0.70710678118654752f;
    {
        int tt = tq + lm;
#pragma unroll
        for (int i = 0; i < 8; ++i) {
            int co = i * 16 + quad * 4;
            short4 hv = *(const short4*)(HT + tt * 136 + co);
            short4 ho;
            ho.x = f2b((b2f(hv.x) + aR[i][0]) * scale);
            ho.y = f2b((b2f(hv.y) + aR[i][1]) * scale);
            ho.z = f2b((b2f(hv.z) + aR[i][2]) * scale);
            ho.w = f2b((b2f(hv.w) + aR[i][3]) * scale);
            *(short4*)(HT + tt * 136 + co) = ho;
        }
    }
    __syncthreads();

    // ---- coalesced h_out copy + z write
    short* hob = hout + (size_t)b * TLEN * CH;
    for (int u = tid; u < 1024; u += 256) {
        int tt = u >> 4, kg = u & 15;
        *(int4*)(hob + (size_t)(t0 + tt) * CH + kg * 8) = HT4[tt * 17 + kg];
    }
    short* zb = zlay + (size_t)b * TPRIME * ZK;
    for (int u = tid; u < 512; u += 256) {
        int tt = u >> 3, kg = u & 7;
        int ts = t0 + tt - LDIFF;
        if ((unsigned)ts < TPRIME)
            *(int4*)(zb + (size_t)ts * ZK + kg * 8) = *(const int4*)(SZ + (kg * 64 + tt) * 8);
    }
}

// ---------------------------------------------------------------- fused skip GEMM + relu -> sbf (PROVEN r9)
__global__ __launch_bounds__(256) void k_skipgemm(
    const short* __restrict__ zbuf,   // [b][t'][1920]
    const short* __restrict__ Wsp,    // [kg240][co128][j8]
    short* __restrict__ sbf) {        // [b][t'][128]
    const int tid = threadIdx.x;
    const int l = tid & 63;
    const int w = tid >> 6;
    const int lm = l & 15;
    const int quad = l >> 4;
    const int b = blockIdx.y;
    const int t0 = blockIdx.x * 64;
    const int coq = (w & 1) * 64;
    const int tq = (w >> 1) * 32;
    const short* zb = zbuf + (size_t)b * TPRIME * ZK;
    const bf16x8* Wsg = (const bf16x8*)Wsp;

    f32x4 acc[4][2] = {};
    for (int kc = 0; kc < 60; ++kc) {
        bf16x8 af[4], bfr[2];
#pragma unroll
        for (int i = 0; i < 4; ++i)
            af[i] = Wsg[(kc * 4 + quad) * 128 + coq + i * 16 + lm];
#pragma unroll
        for (int j = 0; j < 2; ++j) {
            int tg = t0 + tq + j * 16 + lm;
            bf16x8 v = {};
            if (tg < TPRIME)
                v = *(const bf16x8*)(zb + (size_t)tg * ZK + kc * 32 + quad * 8);
            bfr[j] = v;
        }
#pragma unroll
        for (int i = 0; i < 4; ++i)
#pragma unroll
            for (int j = 0; j < 2; ++j)
                acc[i][j] = MFMA(af[i], bfr[j], acc[i][j]);
    }
    short* sb = sbf + (size_t)b * TPRIME * CH;
#pragma unroll
    for (int i = 0; i < 4; ++i)
#pragma unroll
        for (int j = 0; j < 2; ++j) {
            int tg = t0 + tq + j * 16 + lm;
            int co = coq + i * 16 + quad * 4;
            if (tg < TPRIME) {
                short4 v;
                v.x = f2b(fmaxf(acc[i][j][0], 0.f));
                v.y = f2b(fmaxf(acc[i][j][1], 0.f));
                v.z = f2b(fmaxf(acc[i][j][2], 0.f));
                v.w = f2b(fmaxf(acc[i][j][3], 0.f));
                *(short4*)(sb + (size_t)tg * CH + co) = v;
            }
        }
}

// ---------------------------------------------------------------- fused head (r9 + K-split x8)
__global__ __launch_bounds__(256) void k_head(
    const short* __restrict__ sbf,
    const short* __restrict__ Wp1,   // [16][3][4][4][128][8]
    const short* __restrict__ Wp2,   // [2][3][64][4][128][8]
    const float* __restrict__ Wlast,
    float* __restrict__ out) {
    __shared__ __align__(16) char smem[36448];   // SB1 18496 + Y 17952
    int4*  SB1 = (int4*)smem;                    // [68 rows][17 int4]
    short* Y   = (short*)(smem + 18496);         // [66 rows][136 shorts]
    __shared__ float red[64];
    const int tid = threadIdx.x;
    const int l = tid & 63;
    const int w = tid >> 6;
    const int lm = l & 15;
    const int quad = l >> 4;
    const int ks = blockIdx.y;                   // 8 splits x 2 cic
    const int b = blockIdx.z;
    const int t0 = blockIdx.x * 64;
    const short* sb = sbf + (size_t)b * TPRIME * CH;

    for (int u = tid; u < 1088; u += 256) {
        int tt = u >> 4, kg = u & 15;
        int tg = t0 - 2 + tt;
        int4 v = make_int4(0, 0, 0, 0);
        if ((unsigned)tg < TPRIME)
            v = *(const int4*)(sb + (size_t)tg * CH + kg * 8);
        SB1[tt * 17 + kg] = v;
    }
    if (tid < 64) red[tid] = 0.f;
    __syncthreads();

    const bf16x8* W1 = (const bf16x8*)Wp1;
    const bf16x8* W2 = (const bf16x8*)Wp2;
    const int cob2 = w >> 1;
    const int coq2 = (w & 1) * 64;
    f32x4 acc2[4][4] = {};

    for (int cic = ks * 2; cic < ks * 2 + 2; ++cic) {
        f32x4 acc1[2][5] = {};
#pragma unroll
        for (int tap = 0; tap < 3; ++tap)
#pragma unroll
            for (int kc = 0; kc < 4; ++kc) {
                bf16x8 a1[2], b1[5];
#pragma unroll
                for (int i = 0; i < 2; ++i)
                    a1[i] = W1[((size_t)(cic * 3 + tap) * 4 + kc) * 512 +
                               quad * 128 + 32 * w + i * 16 + lm];
#pragma unroll
                for (int j = 0; j < 5; ++j) {
                    int r = j * 16 + lm + tap;
                    b1[j] = *(const bf16x8*)(SB1 + r * 17 + kc * 4 + quad);
                }
#pragma unroll
                for (int i = 0; i < 2; ++i)
#pragma unroll
                    for (int j = 0; j < 5; ++j)
                        acc1[i][j] = MFMA(a1[i], b1[j], acc1[i][j]);
            }
        __syncthreads();
#pragma unroll
        for (int i = 0; i < 2; ++i)
#pragma unroll
            for (int j = 0; j < 5; ++j) {
                int row = j * 16 + lm;
                if (row < 66) {
                    int co = 32 * w + i * 16 + quad * 4;
                    const bool valid = (unsigned)(t0 - 1 + row) < TPRIME;  // zero-pad edges
                    short4 v;
                    v.x = valid ? f2b(fmaxf(acc1[i][j][0], 0.f)) : (short)0;
                    v.y = valid ? f2b(fmaxf(acc1[i][j][1], 0.f)) : (short)0;
                    v.z = valid ? f2b(fmaxf(acc1[i][j][2], 0.f)) : (short)0;
                    v.w = valid ? f2b(fmaxf(acc1[i][j][3], 0.f)) : (short)0;
                    *(short4*)(Y + row * 136 + co) = v;
                }
            }
        __syncthreads();
#pragma unroll
        for (int tap = 0; tap < 3; ++tap)
#pragma unroll
            for (int kc = 0; kc < 4; ++kc) {
                bf16x8 a2[4], b2[4];
#pragma unroll
                for (int i = 0; i < 4; ++i)
                    a2[i] = W2[((size_t)(cob2 * 3 + tap) * 64 + cic * 4 + kc) * 512 +
                               quad * 128 + coq2 + i * 16 + lm];
#pragma unroll
                for (int j = 0; j < 4; ++j) {
                    int row = j * 16 + lm + tap;
                    b2[j] = *(const bf16x8*)(Y + row * 136 + kc * 32 + quad * 8);
                }
#pragma unroll
                for (int i = 0; i < 4; ++i)
#pragma unroll
                    for (int j = 0; j < 4; ++j)
                        acc2[i][j] = MFMA(a2[i], b2[j], acc2[i][j]);
            }
    }

    float4 wv[4];
#pragma unroll
    for (int i = 0; i < 4; ++i)
        wv[i] = *(const float4*)(Wlast + cob2 * 128 + coq2 + i * 16 + quad * 4);
#pragma unroll
    for (int j = 0; j < 4; ++j) {
        float s = 0.f;
#pragma unroll
        for (int i = 0; i < 4; ++i)
            s += wv[i].x * acc2[i][j][0] + wv[i].y * acc2[i][j][1] +
                 wv[i].z * acc2[i][j][2] + wv[i].w * acc2[i][j][3];
        atomicAdd(&red[j * 16 + lm], s);
    }
    __syncthreads();
    if (tid < 64) {
        int tg = t0 + tid;
        if (tg < TPRIME) atomicAdd(&out[(size_t)b * TPRIME + tg], red[tid]);
    }
}

// ---------------------------------------------------------------- bias init (PROVEN r4)
__global__ void k_bias(float* __restrict__ out, const float* __restrict__ bl) {
    int i = blockIdx.x * 256 + threadIdx.x;
    if (i < BATCH * TPRIME) out[i] = bl[0];
}

extern "C" void kernel_launch(void* const* d_in, const int* in_sizes, int n_in,
                              void* d_out, int out_size, void* d_ws, size_t ws_size,
                              hipStream_t stream) {
    const float* x = (const float*)d_in[0];
    const float* Wf = (const float*)d_in[1];
    const float* Wdil = (const float*)d_in[2];
    const float* Wskip = (const float*)d_in[3];
    const float* Wres = (const float*)d_in[4];
    const float* Wfc1 = (const float*)d_in[5];
    const float* Wfc2 = (const float*)d_in[6];
    const float* Wlast = (const float*)d_in[7];
    const float* blast = (const float*)d_in[8];
    float* out = (float*)d_out;

    char* p = (char*)d_ws;
    auto alloc = [&](size_t bytes) { char* r = p; p += (bytes + 255) & ~(size_t)255; return r; };
    short* zbuf  = (short*)alloc((size_t)BATCH * TPRIME * ZK * 2);   // 157.4 MB
    short* WpD   = (short*)alloc((size_t)NLAYERS * 49152 * 2);       // 2.95 MB
    short* Wsp   = (short*)alloc((size_t)NLAYERS * 8192 * 2);        // 0.49 MB (K-major image)
    short* Wrp   = (short*)alloc((size_t)NLAYERS * 8192 * 2);        // 0.49 MB
    short* Wp1   = (short*)alloc((size_t)786432 * 2);                // 1.5 MB
    short* Wp2   = (short*)alloc((size_t)1572864 * 2);               // 3.0 MB
    short* hA    = (short*)alloc((size_t)BATCH * TLEN * CH * 2);     // 16.78 MB
    short* hB    = (short*)alloc((size_t)BATCH * TLEN * CH * 2);     // 16.78 MB
    short* sbf   = (short*)alloc((size_t)BATCH * TPRIME * CH * 2);   // 10.49 MB
    // total ~210 MB

    k_prep_conv<<<5760, 256, 0, stream>>>(Wdil, WpD, 128, 4, 1474560);
    k_prep_conv<<<3072, 256, 0, stream>>>(Wfc1, Wp1, 128, 4, 786432);
    k_prep_conv<<<6144, 256, 0, stream>>>(Wfc2, Wp2, 2048, 64, 1572864);
    k_prep_sr<<<960, 256, 0, stream>>>(Wskip, Wres, Wsp, Wrp);
    k_first<<<8192, 256, 0, stream>>>(x, Wf, hA);

    short* hin = hA;
    short* hout = hB;
    for (int lyr = 0; lyr < NLAYERS; ++lyr) {
        int d = 1 << (lyr % 10);
        k_layer<<<dim3(TLEN / 64, BATCH), 256, 0, stream>>>(
            hin, hout, zbuf + (size_t)lyr * 64,
            WpD + (size_t)lyr * 49152, Wrp + (size_t)lyr * 8192, d);
        short* tmp = hin; hin = hout; hout = tmp;
    }

    k_skipgemm<<<dim3(161, BATCH), 256, 0, stream>>>(zbuf, Wsp, sbf);
    k_bias<<<161, 256, 0, stream>>>(out, blast);
    k_head<<<dim3(161, 8, BATCH), 256, 0, stream>>>(sbf, Wp1, Wp2, Wlast, out);
}